// Round 22
// baseline (69.873 us; speedup 1.0000x reference)
//
#include <hip/hip_runtime.h>
#include <hip/hip_bf16.h>

#define B_Q 4096
#define R_T 500
#define D_E 64
#define N_N 100000
#define E_E 3200000
#define BM_W ((N_N + 31) / 32)   // 3125 words = 12.5 KB LDS bitmap
#define SCAT_B 512               // scatter role blocks (proven optimum)
#define RF_B   64                // rel_freq role blocks (concurrent)
#define ZERO_B 2000              // Cm-zeroing role blocks in k_prep

typedef int   iv4 __attribute__((ext_vector_type(4)));
typedef float fv4 __attribute__((ext_vector_type(4)));

// ws layout (ints): Cm[B*R] | rel_freq[R] | slot[N]
#define OFF_RF   ((size_t)B_Q * R_T)
#define OFF_SLOT (OFF_RF + R_T)

// ---------------------------------------------------------------------------
// k_prep (role-split, disjoint memory):
//  role A [0,2000):  zero Cm + rel_freq
//  role B [2000,2016): slot[qents[b]] = b (plain store; any winner valid)
// ---------------------------------------------------------------------------
__global__ __launch_bounds__(256) void k_prep(const int* __restrict__ qents,
                                              int* __restrict__ ws) {
    if (blockIdx.x < ZERO_B) {
        const int t = blockIdx.x * 256 + threadIdx.x;   // [0, 512000)
        ((uint4*)ws)[t] = make_uint4(0u, 0u, 0u, 0u);
        if (t < R_T) ws[OFF_RF + t] = 0;
    } else {
        const int b = (blockIdx.x - ZERO_B) * 256 + threadIdx.x;  // [0, 4096)
        ws[OFF_SLOT + qents[b]] = b;
    }
}

// ---------------------------------------------------------------------------
// ROLE-SPLIT dispatch: blocks [0,512) scatter (LDS bitmap built from qents);
// blocks [512,576) rel_freq histogram (hides under scatter).
// ---------------------------------------------------------------------------
__global__ __launch_bounds__(256) void k_edge_scatter(const int* __restrict__ ei,
                                                      const int* __restrict__ et,
                                                      const int* __restrict__ qents,
                                                      int* __restrict__ ws) {
    __shared__ int      hist[R_T];
    __shared__ unsigned sbm[BM_W];

    if (blockIdx.x < SCAT_B) {
        for (int i = threadIdx.x; i < BM_W; i += 256) sbm[i] = 0u;
        __syncthreads();
        for (int i = threadIdx.x; i < B_Q; i += 256) {
            const int q = qents[i];
            atomicOr(&sbm[q >> 5], 1u << (q & 31));
        }
        __syncthreads();

        const int* __restrict__ slot = ws + OFF_SLOT;
        int* __restrict__       Cm   = ws;

        const int nthr = SCAT_B * 256;
        const int t    = blockIdx.x * 256 + threadIdx.x;
        for (int g = t; g < E_E / 4; g += nthr) {
            const int e0 = g * 4;
            const iv4 s4 = *(const iv4*)(ei + e0);
            const iv4 d4 = *(const iv4*)(ei + E_E + e0);
            const iv4 t4 = *(const iv4*)(et + e0);
            #pragma unroll
            for (int j = 0; j < 4; ++j) {
                const int s  = s4[j];
                const int d  = d4[j];
                const int ty = t4[j];
                if ((sbm[s >> 5] >> (s & 31)) & 1u) {
                    atomicAdd(&Cm[(size_t)slot[s] * R_T + ty], 1);
                }
                if (d != s && ((sbm[d >> 5] >> (d & 31)) & 1u)) {
                    atomicAdd(&Cm[(size_t)slot[d] * R_T + ty], 1);
                }
            }
        }
    } else {
        for (int i = threadIdx.x; i < R_T; i += blockDim.x) hist[i] = 0;
        __syncthreads();

        const int nthr = RF_B * 256;
        const int t    = (blockIdx.x - SCAT_B) * 256 + threadIdx.x;
        for (int g = t; g < E_E / 4; g += nthr) {
            const iv4 t4 = *(const iv4*)(et + g * 4);
            #pragma unroll
            for (int j = 0; j < 4; ++j) atomicAdd(&hist[t4[j]], 1);
        }
        __syncthreads();
        for (int i = threadIdx.x; i < R_T; i += blockDim.x) {
            int v = hist[i];
            if (v) atomicAdd(&ws[OFF_RF + i], v);
        }
    }
}

// ---------------------------------------------------------------------------
// TWO waves per query (grid = B/2 blocks x 256 = 32 waves/CU, chip max TLP):
//  - both waves run the compaction scan redundantly (identical writes,
//    each wave reads only entries it wrote itself; degl known to both)
//  - gather split by wave parity (k = p*8 step 16) -> serial iters halved
//  - partials combine via sEnt LDS + 2 barriers; wave0 runs the MLP
// ---------------------------------------------------------------------------
__global__ __launch_bounds__(256) void k_gate(
    const float* __restrict__ RE,
    const int* __restrict__ qrels, const int* __restrict__ qents,
    const int* __restrict__ ws,
    const float* __restrict__ W1, const float* __restrict__ b1,
    const float* __restrict__ W2, const float* __restrict__ b2,
    const float* __restrict__ W3, const float* __restrict__ b3,
    const float* __restrict__ W4, const float* __restrict__ b4,
    float* __restrict__ out)
{
    __shared__ int   sIdx[2][512];
    __shared__ float sCnt[2][512];
    __shared__ float sEnt[2][64];
    __shared__ float sF [2][132];
    __shared__ float sH1[2][64];
    __shared__ float sH2[2][32];
    __shared__ float sG [2][16];

    const int wid  = threadIdx.x >> 6;      // 0..3
    const int lane = threadIdx.x & 63;
    const int qi   = wid >> 1;              // query slot in block: 0..1
    const int wp   = wid & 1;               // wave parity within pair
    const int b    = blockIdx.x * 2 + qi;   // grid = B_Q/2

    const int q  = qents[b];
    const int qr = qrels[b];
    const int sl = ws[OFF_SLOT + q];
    const int* __restrict__   crow = ws + (size_t)sl * R_T;
    const float* __restrict__ REb  = RE + (size_t)b * (R_T * D_E);

    if (wp == 0) sF[qi][lane] = REb[qr * D_E + lane];   // stage reb early

    // --- compaction scan (both waves, redundant identical writes) ---
    int nnz = 0, degl = 0;
    for (int base = 0; base < R_T; base += 64) {
        int r = base + lane;
        int c = (r < R_T) ? crow[r] : 0;
        degl += c;
        unsigned long long m = __ballot(c != 0);
        if (c != 0) {
            int pos = nnz + (int)__popcll(m & ((1ull << lane) - 1ull));
            sIdx[qi][pos] = r;
            sCnt[qi][pos] = (float)c;
        }
        nnz += (int)__popcll(m);
    }
    if (lane < 8) {                 // pad to 8 (both waves, same values)
        sIdx[qi][nnz + lane] = 0;
        sCnt[qi][nnz + lane] = 0.f;
    }
    #pragma unroll
    for (int off = 32; off; off >>= 1) degl += __shfl_xor(degl, off, 64);

    // --- gather: wave wp handles k = wp*8, step 16 (8 rows/iter) ---
    const int g8 = lane >> 3;
    const int l8 = lane & 7;
    fv4 acc0 = {0.f, 0.f, 0.f, 0.f};
    fv4 acc1 = {0.f, 0.f, 0.f, 0.f};
    for (int k = wp * 8; k < nnz; k += 16) {
        int   r = sIdx[qi][k + g8];
        float c = sCnt[qi][k + g8];
        const float* p = REb + r * D_E + 8 * l8;
        fv4 v0 = *(const fv4*)(p);
        fv4 v1 = *(const fv4*)(p + 4);
        acc0[0] = fmaf(c, v0[0], acc0[0]);
        acc0[1] = fmaf(c, v0[1], acc0[1]);
        acc0[2] = fmaf(c, v0[2], acc0[2]);
        acc0[3] = fmaf(c, v0[3], acc0[3]);
        acc1[0] = fmaf(c, v1[0], acc1[0]);
        acc1[1] = fmaf(c, v1[1], acc1[1]);
        acc1[2] = fmaf(c, v1[2], acc1[2]);
        acc1[3] = fmaf(c, v1[3], acc1[3]);
    }
    #pragma unroll
    for (int off = 8; off <= 32; off <<= 1) {
        acc0[0] += __shfl_xor(acc0[0], off, 64);
        acc0[1] += __shfl_xor(acc0[1], off, 64);
        acc0[2] += __shfl_xor(acc0[2], off, 64);
        acc0[3] += __shfl_xor(acc0[3], off, 64);
        acc1[0] += __shfl_xor(acc1[0], off, 64);
        acc1[1] += __shfl_xor(acc1[1], off, 64);
        acc1[2] += __shfl_xor(acc1[2], off, 64);
        acc1[3] += __shfl_xor(acc1[3], off, 64);
    }

    // --- cross-wave combine ---
    if (wp == 0 && lane < 8) {
        *(float4*)&sEnt[qi][8 * lane]     = make_float4(acc0[0], acc0[1], acc0[2], acc0[3]);
        *(float4*)&sEnt[qi][8 * lane + 4] = make_float4(acc1[0], acc1[1], acc1[2], acc1[3]);
    }
    __syncthreads();

    const float tot = (float)degl;
    const float inv = (degl > 0) ? (1.f / tot) : 0.f;

    if (wp == 1) {
        if (lane < 8) {
            float4 p0 = *(float4*)&sEnt[qi][8 * lane];
            float4 p1 = *(float4*)&sEnt[qi][8 * lane + 4];
            float4* dst0 = (float4*)&sF[qi][64 + 8 * lane];
            float4* dst1 = (float4*)&sF[qi][64 + 8 * lane + 4];
            *dst0 = make_float4((p0.x + acc0[0]) * inv, (p0.y + acc0[1]) * inv,
                                (p0.z + acc0[2]) * inv, (p0.w + acc0[3]) * inv);
            *dst1 = make_float4((p1.x + acc1[0]) * inv, (p1.y + acc1[1]) * inv,
                                (p1.z + acc1[2]) * inv, (p1.w + acc1[3]) * inv);
        }
        if (lane == 0) {
            const float invE = (float)(1.0 / (double)E_E);
            float rf   = fminf((float)ws[OFF_RF + qr] * invE, 1.f);
            float dn   = fminf(tot * invE, 1.f);
            float dens = fminf((float)((double)E_E / ((double)N_N * (double)N_N)), 1.f);
            sF[qi][128] = rf;
            sF[qi][129] = dn;
            sF[qi][130] = rf;
            sF[qi][131] = dens;
        }
    }
    __syncthreads();

    // --- MLP (wave0 only; all LDS traffic intra-wave from here) ---
    if (wp == 0) {
        float h = b1[lane];
        #pragma unroll 4
        for (int i = 0; i < 2 * D_E + 4; ++i)
            h = fmaf(sF[qi][i], W1[i * D_E + lane], h);
        sH1[qi][lane] = fmaxf(h, 0.f);

        if (lane < 32) {
            float s2 = b2[lane];
            #pragma unroll 4
            for (int i = 0; i < D_E; ++i)
                s2 = fmaf(sH1[qi][i], W2[i * 32 + lane], s2);
            sH2[qi][lane] = fmaxf(s2, 0.f);
        }

        if (lane < 16) {
            float s3 = b3[lane];
            #pragma unroll
            for (int i = 0; i < 32; ++i)
                s3 = fmaf(sH2[qi][i], W3[i * 16 + lane], s3);
            sG[qi][lane] = fmaxf(s3, 0.f);
        }

        if (lane == 0) {
            float s4 = b4[0];
            #pragma unroll
            for (int i = 0; i < 16; ++i)
                s4 = fmaf(sG[qi][i], W4[i], s4);
            out[b] = 1.f / (1.f + expf(-s4));
        }
    }
}

extern "C" void kernel_launch(void* const* d_in, const int* in_sizes, int n_in,
                              void* d_out, int out_size, void* d_ws, size_t ws_size,
                              hipStream_t stream) {
    const float* RE    = (const float*)d_in[0];
    const int*   qrels = (const int*)d_in[1];
    const int*   qents = (const int*)d_in[2];
    const int*   ei    = (const int*)d_in[3];
    const int*   et    = (const int*)d_in[4];
    const float* W1    = (const float*)d_in[5];
    const float* b1    = (const float*)d_in[6];
    const float* W2    = (const float*)d_in[7];
    const float* b2    = (const float*)d_in[8];
    const float* W3    = (const float*)d_in[9];
    const float* b3    = (const float*)d_in[10];
    const float* W4    = (const float*)d_in[11];
    const float* b4    = (const float*)d_in[12];
    float* out = (float*)d_out;
    int*   ws  = (int*)d_ws;

    k_prep<<<ZERO_B + 16, 256, 0, stream>>>(qents, ws);
    k_edge_scatter<<<SCAT_B + RF_B, 256, 0, stream>>>(ei, et, qents, ws);
    k_gate<<<B_Q / 2, 256, 0, stream>>>(RE, qrels, qents, ws,
                                        W1, b1, W2, b2, W3, b3, W4, b4, out);
}

// Round 23
// 69.003 us; speedup vs baseline: 1.0126x; 1.0126x over previous
//
#include <hip/hip_runtime.h>
#include <hip/hip_bf16.h>

#define B_Q 4096
#define R_T 500
#define D_E 64
#define N_N 100000
#define E_E 3200000
#define BM_W ((N_N + 31) / 32)   // 3125 words = 12.5 KB LDS bitmap
#define SCAT_B 512               // scatter role blocks (proven optimum)
#define RF_B   64                // rel_freq role blocks (concurrent)
#define ZERO_B 1000              // Cm-zeroing role blocks (u16 Cm = 4.1MB)

typedef int   iv4 __attribute__((ext_vector_type(4)));
typedef float fv4 __attribute__((ext_vector_type(4)));

// ws layout (int units): Cm_u16[B*R] (= B*R/2 ints) | rel_freq[R] | slot[N]
#define OFF_RF   ((size_t)B_Q * R_T / 2)
#define OFF_SLOT (OFF_RF + R_T)

// ---------------------------------------------------------------------------
// k_prep (role-split, disjoint memory):
//  role A [0,1000):  zero Cm (1.024M words as 256K uint4) + rel_freq
//  role B [1000,1016): slot[qents[b]] = b (plain store; any winner valid)
// ---------------------------------------------------------------------------
__global__ __launch_bounds__(256) void k_prep(const int* __restrict__ qents,
                                              int* __restrict__ ws) {
    if (blockIdx.x < ZERO_B) {
        const int t = blockIdx.x * 256 + threadIdx.x;   // [0, 256000)
        ((uint4*)ws)[t] = make_uint4(0u, 0u, 0u, 0u);   // Cm = 256000 uint4 exact
        if (t < R_T) ws[OFF_RF + t] = 0;
    } else {
        const int b = (blockIdx.x - ZERO_B) * 256 + threadIdx.x;  // [0, 4096)
        ws[OFF_SLOT + qents[b]] = b;
    }
}

// ---------------------------------------------------------------------------
// ROLE-SPLIT dispatch: blocks [0,512) scatter (LDS bitmap built from qents,
// u16-packed Cm atomics); blocks [512,576) rel_freq histogram.
// ---------------------------------------------------------------------------
__global__ __launch_bounds__(256) void k_edge_scatter(const int* __restrict__ ei,
                                                      const int* __restrict__ et,
                                                      const int* __restrict__ qents,
                                                      int* __restrict__ ws) {
    __shared__ int      hist[R_T];
    __shared__ unsigned sbm[BM_W];

    if (blockIdx.x < SCAT_B) {
        for (int i = threadIdx.x; i < BM_W; i += 256) sbm[i] = 0u;
        __syncthreads();
        for (int i = threadIdx.x; i < B_Q; i += 256) {
            const int q = qents[i];
            atomicOr(&sbm[q >> 5], 1u << (q & 31));
        }
        __syncthreads();

        const int* __restrict__ slot = ws + OFF_SLOT;
        unsigned* __restrict__  Cm   = (unsigned*)ws;

        const int nthr = SCAT_B * 256;
        const int t    = blockIdx.x * 256 + threadIdx.x;
        for (int g = t; g < E_E / 4; g += nthr) {
            const int e0 = g * 4;
            const iv4 s4 = *(const iv4*)(ei + e0);
            const iv4 d4 = *(const iv4*)(ei + E_E + e0);
            const iv4 t4 = *(const iv4*)(et + e0);
            #pragma unroll
            for (int j = 0; j < 4; ++j) {
                const int s  = s4[j];
                const int d  = d4[j];
                const int ty = t4[j];
                if ((sbm[s >> 5] >> (s & 31)) & 1u) {
                    const size_t idx = (size_t)slot[s] * R_T + ty;
                    atomicAdd(&Cm[idx >> 1], 1u << ((idx & 1) * 16));
                }
                if (d != s && ((sbm[d >> 5] >> (d & 31)) & 1u)) {
                    const size_t idx = (size_t)slot[d] * R_T + ty;
                    atomicAdd(&Cm[idx >> 1], 1u << ((idx & 1) * 16));
                }
            }
        }
    } else {
        for (int i = threadIdx.x; i < R_T; i += blockDim.x) hist[i] = 0;
        __syncthreads();

        const int nthr = RF_B * 256;
        const int t    = (blockIdx.x - SCAT_B) * 256 + threadIdx.x;
        for (int g = t; g < E_E / 4; g += nthr) {
            const iv4 t4 = *(const iv4*)(et + g * 4);
            #pragma unroll
            for (int j = 0; j < 4; ++j) atomicAdd(&hist[t4[j]], 1);
        }
        __syncthreads();
        for (int i = threadIdx.x; i < R_T; i += blockDim.x) {
            int v = hist[i];
            if (v) atomicAdd(&ws[OFF_RF + i], v);
        }
    }
}

// ---------------------------------------------------------------------------
// One wave per query; 4 waves/block, ZERO block barriers (R21-proven shape).
// Count scan reads 250 u32 words (2 packed u16 counts each): 4 rounds,
// 2 ballots/round, exact ascending-r compaction order preserved.
// Gather: 8 rows/iter, 2 fv4 loads/lane (R18-proven).
// ---------------------------------------------------------------------------
__global__ __launch_bounds__(256) void k_gate(
    const float* __restrict__ RE,
    const int* __restrict__ qrels, const int* __restrict__ qents,
    const int* __restrict__ ws,
    const float* __restrict__ W1, const float* __restrict__ b1,
    const float* __restrict__ W2, const float* __restrict__ b2,
    const float* __restrict__ W3, const float* __restrict__ b3,
    const float* __restrict__ W4, const float* __restrict__ b4,
    float* __restrict__ out)
{
    __shared__ int   sIdx[4][512];
    __shared__ float sCnt[4][512];
    __shared__ float sF [4][132];
    __shared__ float sH1[4][64];
    __shared__ float sH2[4][32];
    __shared__ float sG [4][16];

    const int wid  = threadIdx.x >> 6;
    const int lane = threadIdx.x & 63;
    const int b    = blockIdx.x * 4 + wid;   // grid is exactly B/4

    const int q  = qents[b];
    const int qr = qrels[b];
    const int sl = ws[OFF_SLOT + q];
    const unsigned* __restrict__ crow = (const unsigned*)ws + (size_t)sl * (R_T / 2);
    const float* __restrict__    REb  = RE + (size_t)b * (R_T * D_E);

    float reb = REb[qr * D_E + lane];

    // --- compact nonzero counts from packed u16 pairs (ascending r) ---
    int nnz = 0, degl = 0;
    const unsigned long long below = (1ull << lane) - 1ull;
    #pragma unroll
    for (int base = 0; base < 256; base += 64) {
        const int w = base + lane;
        const unsigned cw = (w < R_T / 2) ? crow[w] : 0u;
        const int c0 = (int)(cw & 0xffffu);      // r = 2w
        const int c1 = (int)(cw >> 16);          // r = 2w+1
        degl += c0 + c1;
        unsigned long long m0 = __ballot(c0 != 0);
        unsigned long long m1 = __ballot(c1 != 0);
        if (c0) {
            int pos = nnz + (int)__popcll(m0 & below) + (int)__popcll(m1 & below);
            sIdx[wid][pos] = 2 * w;
            sCnt[wid][pos] = (float)c0;
        }
        if (c1) {
            int pos = nnz + (int)__popcll(m0 & (below | (1ull << lane)))
                          + (int)__popcll(m1 & below);
            sIdx[wid][pos] = 2 * w + 1;
            sCnt[wid][pos] = (float)c1;
        }
        nnz += (int)__popcll(m0) + (int)__popcll(m1);
    }
    // pad to multiple of 8 with zero-count entries
    if (lane < 8) {
        sIdx[wid][nnz + lane] = 0;
        sCnt[wid][nnz + lane] = 0.f;
    }
    #pragma unroll
    for (int off = 32; off; off >>= 1) degl += __shfl_xor(degl, off, 64);

    // --- sparse weighted sum: 8 rows/iter, 2 fv4 loads/lane, branch-free ---
    const int g8 = lane >> 3;
    const int l8 = lane & 7;
    fv4 acc0 = {0.f, 0.f, 0.f, 0.f};
    fv4 acc1 = {0.f, 0.f, 0.f, 0.f};
    #pragma unroll 2
    for (int k = 0; k < nnz; k += 8) {
        int   r = sIdx[wid][k + g8];
        float c = sCnt[wid][k + g8];
        const float* p = REb + r * D_E + 8 * l8;
        fv4 v0 = *(const fv4*)(p);
        fv4 v1 = *(const fv4*)(p + 4);
        acc0[0] = fmaf(c, v0[0], acc0[0]);
        acc0[1] = fmaf(c, v0[1], acc0[1]);
        acc0[2] = fmaf(c, v0[2], acc0[2]);
        acc0[3] = fmaf(c, v0[3], acc0[3]);
        acc1[0] = fmaf(c, v1[0], acc1[0]);
        acc1[1] = fmaf(c, v1[1], acc1[1]);
        acc1[2] = fmaf(c, v1[2], acc1[2]);
        acc1[3] = fmaf(c, v1[3], acc1[3]);
    }
    #pragma unroll
    for (int off = 8; off <= 32; off <<= 1) {
        acc0[0] += __shfl_xor(acc0[0], off, 64);
        acc0[1] += __shfl_xor(acc0[1], off, 64);
        acc0[2] += __shfl_xor(acc0[2], off, 64);
        acc0[3] += __shfl_xor(acc0[3], off, 64);
        acc1[0] += __shfl_xor(acc1[0], off, 64);
        acc1[1] += __shfl_xor(acc1[1], off, 64);
        acc1[2] += __shfl_xor(acc1[2], off, 64);
        acc1[3] += __shfl_xor(acc1[3], off, 64);
    }

    const float tot = (float)degl;
    const float inv = (degl > 0) ? (1.f / tot) : 0.f;

    sF[wid][lane] = reb;
    if (lane < 8) {
        float4* dst0 = (float4*)&sF[wid][64 + 8 * lane];
        float4* dst1 = (float4*)&sF[wid][64 + 8 * lane + 4];
        *dst0 = make_float4(acc0[0] * inv, acc0[1] * inv, acc0[2] * inv, acc0[3] * inv);
        *dst1 = make_float4(acc1[0] * inv, acc1[1] * inv, acc1[2] * inv, acc1[3] * inv);
    }
    if (lane == 0) {
        const float invE = (float)(1.0 / (double)E_E);
        float rf   = fminf((float)ws[OFF_RF + qr] * invE, 1.f);
        float dn   = fminf(tot * invE, 1.f);
        float dens = fminf((float)((double)E_E / ((double)N_N * (double)N_N)), 1.f);
        sF[wid][128] = rf;
        sF[wid][129] = dn;
        sF[wid][130] = rf;
        sF[wid][131] = dens;
    }
    // (no barrier: same-wave LDS write->read is in-order)

    // --- layer 1: 132 -> 64 ---
    float h = b1[lane];
    #pragma unroll 4
    for (int i = 0; i < 2 * D_E + 4; ++i)
        h = fmaf(sF[wid][i], W1[i * D_E + lane], h);
    sH1[wid][lane] = fmaxf(h, 0.f);

    // --- layer 2: 64 -> 32 ---
    if (lane < 32) {
        float s2 = b2[lane];
        #pragma unroll 4
        for (int i = 0; i < D_E; ++i)
            s2 = fmaf(sH1[wid][i], W2[i * 32 + lane], s2);
        sH2[wid][lane] = fmaxf(s2, 0.f);
    }

    // --- layer 3: 32 -> 16 ---
    if (lane < 16) {
        float s3 = b3[lane];
        #pragma unroll
        for (int i = 0; i < 32; ++i)
            s3 = fmaf(sH2[wid][i], W3[i * 16 + lane], s3);
        sG[wid][lane] = fmaxf(s3, 0.f);
    }

    // --- gate: 16 -> 1, sigmoid ---
    if (lane == 0) {
        float s4 = b4[0];
        #pragma unroll
        for (int i = 0; i < 16; ++i)
            s4 = fmaf(sG[wid][i], W4[i], s4);
        out[b] = 1.f / (1.f + expf(-s4));
    }
}

extern "C" void kernel_launch(void* const* d_in, const int* in_sizes, int n_in,
                              void* d_out, int out_size, void* d_ws, size_t ws_size,
                              hipStream_t stream) {
    const float* RE    = (const float*)d_in[0];
    const int*   qrels = (const int*)d_in[1];
    const int*   qents = (const int*)d_in[2];
    const int*   ei    = (const int*)d_in[3];
    const int*   et    = (const int*)d_in[4];
    const float* W1    = (const float*)d_in[5];
    const float* b1    = (const float*)d_in[6];
    const float* W2    = (const float*)d_in[7];
    const float* b2    = (const float*)d_in[8];
    const float* W3    = (const float*)d_in[9];
    const float* b3    = (const float*)d_in[10];
    const float* W4    = (const float*)d_in[11];
    const float* b4    = (const float*)d_in[12];
    float* out = (float*)d_out;
    int*   ws  = (int*)d_ws;

    k_prep<<<ZERO_B + 16, 256, 0, stream>>>(qents, ws);
    k_edge_scatter<<<SCAT_B + RF_B, 256, 0, stream>>>(ei, et, qents, ws);
    k_gate<<<B_Q / 4, 256, 0, stream>>>(RE, qrels, qents, ws,
                                        W1, b1, W2, b2, W3, b3, W4, b4, out);
}